// Round 4
// baseline (621.346 us; speedup 1.0000x reference)
//
#include <hip/hip_runtime.h>
#include <hip/hip_cooperative_groups.h>

namespace cg = cooperative_groups;

#define N_NODES 8192
#define D_IN    128
#define D_OUT   64
#define NSPLIT  8
#define MAXGRID 1024

typedef __attribute__((ext_vector_type(8))) short short8;
typedef __attribute__((ext_vector_type(4))) float f32x4;

__device__ __forceinline__ short f2bf(float f) {
    unsigned u = __builtin_bit_cast(unsigned, f);
    u += 0x7fff + ((u >> 16) & 1);
    return (short)(u >> 16);
}
__device__ __forceinline__ unsigned f2bf_pack(float lo, float hi) {
    unsigned a = __builtin_bit_cast(unsigned, lo);
    a += 0x7fff + ((a >> 16) & 1);
    unsigned b = __builtin_bit_cast(unsigned, hi);
    b += 0x7fff + ((b >> 16) & 1);
    return (a >> 16) | (b & 0xffff0000u);
}

// ---- Phase 1: dis[i] = rsqrt(rowsum(A[i,:])); A16 = bf16(A). One wave/row. ----
__device__ __forceinline__ void phase1(const float* __restrict__ A,
                                       float* __restrict__ dis,
                                       unsigned short* __restrict__ A16,
                                       int bid, int nb, int tid) {
    const int wave = tid >> 6, lane = tid & 63;
    for (int row = bid * 4 + wave; row < N_NODES; row += nb * 4) {
        const float4* Ar = (const float4*)(A + (size_t)row * N_NODES);
        uint2* Aw = (uint2*)(A16 + (size_t)row * N_NODES);
        float s = 0.f;
#pragma unroll
        for (int i = 0; i < 32; ++i) {
            float4 v = Ar[lane + 64 * i];
            s += (v.x + v.y) + (v.z + v.w);
            uint2 p;
            p.x = f2bf_pack(v.x, v.y);
            p.y = f2bf_pack(v.z, v.w);
            Aw[lane + 64 * i] = p;
        }
#pragma unroll
        for (int off = 32; off; off >>= 1) s += __shfl_down(s, off, 64);
        if (lane == 0) dis[row] = rsqrtf(s);
    }
}

// ---- Phase 2: G = (diag(dis)*X)@W packed in MFMA B-frag order (R1-verified layout)
// k=(t,quad,j): t=k>>5, quad=(k>>3)&3, j=k&7;  n=(u,n15): elem at ((t*4+u)*64+quad*16+n15)*8+j
__device__ __forceinline__ void phase2(const float* __restrict__ X,
                                       const float* __restrict__ W,
                                       const float* __restrict__ dis,
                                       unsigned short* __restrict__ Gp,
                                       int bid, int nb, int tid) {
    for (int gid = bid * 256 + tid; gid < N_NODES * 8; gid += nb * 256) {
        const int k = gid >> 3;
        const int n0 = (gid & 7) * 8;
        float acc[8] = {0.f,0.f,0.f,0.f,0.f,0.f,0.f,0.f};
        const float4* Xr = (const float4*)(X + (size_t)k * D_IN);
#pragma unroll 4
        for (int d4 = 0; d4 < 32; ++d4) {
            float4 xv = Xr[d4];
            const float* w = W + (d4 * 4) * D_OUT + n0;
#pragma unroll
            for (int q = 0; q < 4; ++q) {
                float x = (q == 0) ? xv.x : (q == 1) ? xv.y : (q == 2) ? xv.z : xv.w;
                float4 w0 = ((const float4*)(w + q * D_OUT))[0];
                float4 w1 = ((const float4*)(w + q * D_OUT))[1];
                acc[0] += x * w0.x; acc[1] += x * w0.y;
                acc[2] += x * w0.z; acc[3] += x * w0.w;
                acc[4] += x * w1.x; acc[5] += x * w1.y;
                acc[6] += x * w1.z; acc[7] += x * w1.w;
            }
        }
        const float scale = dis[k];
        const int t = k >> 5, quad = (k >> 3) & 3, j = k & 7;
#pragma unroll
        for (int c = 0; c < 8; ++c) {
            int n = n0 + c;
            Gp[(((size_t)t * 4 + (n >> 4)) * 64 + quad * 16 + (n & 15)) * 8 + j] =
                (unsigned short)f2bf(acc[c] * scale);
        }
    }
}

// ---- Phase 3: partial[split] = A16_rowchunk @ G (bf16 MFMA, plain stores) ----
// Work item = (rowchunk 0..63, split 0..7). Block = 4 waves x 32 rows = 128 rows.
__device__ __forceinline__ void phase3(const unsigned short* __restrict__ A16,
                                       const unsigned short* __restrict__ Gp,
                                       float* __restrict__ partial,
                                       int bid, int nb, int tid) {
    const int wave = tid >> 6, lane = tid & 63;
    const int quad = lane >> 4, l15 = lane & 15;
    const short8* Gq = (const short8*)Gp;
    for (int w = bid; w < 64 * NSPLIT; w += nb) {
        const int rowbase = (w & 63) * 128 + wave * 32;
        const int split = w >> 6;
        const short8* Ar0 = (const short8*)(A16 + (size_t)(rowbase + l15) * N_NODES);
        const short8* Ar1 = (const short8*)(A16 + (size_t)(rowbase + 16 + l15) * N_NODES);
        const int kt0 = split * (N_NODES / 32 / NSPLIT);
        f32x4 acc[2][4] = {};
        for (int kt = kt0; kt < kt0 + (N_NODES / 32 / NSPLIT); ++kt) {
            short8 a0 = Ar0[kt * 4 + quad];
            short8 a1 = Ar1[kt * 4 + quad];
            const short8* gb = Gq + (size_t)kt * 256 + lane;
#pragma unroll
            for (int u = 0; u < 4; ++u) {
                short8 b = gb[u * 64];
                acc[0][u] = __builtin_amdgcn_mfma_f32_16x16x32_bf16(a0, b, acc[0][u], 0, 0, 0);
                acc[1][u] = __builtin_amdgcn_mfma_f32_16x16x32_bf16(a1, b, acc[1][u], 0, 0, 0);
            }
        }
        float* P = partial + (size_t)split * (N_NODES * D_OUT);
#pragma unroll
        for (int rt = 0; rt < 2; ++rt)
#pragma unroll
            for (int u = 0; u < 4; ++u)
#pragma unroll
                for (int r = 0; r < 4; ++r)
                    P[(size_t)(rowbase + rt * 16 + quad * 4 + r) * D_OUT + u * 16 + l15] =
                        acc[rt][u][r];
    }
}

// ---- Phase 4: out = relu(dis[row] * sum_s partial[s]) ----
__device__ __forceinline__ void phase4(const float* __restrict__ partial,
                                       const float* __restrict__ dis,
                                       float* __restrict__ out,
                                       int bid, int nb, int tid) {
    for (int gid = bid * 256 + tid; gid < N_NODES * D_OUT / 4; gid += nb * 256) {
        const float4* p4 = (const float4*)partial;
        float4 s = p4[gid];
#pragma unroll
        for (int sp = 1; sp < NSPLIT; ++sp) {
            float4 v = p4[gid + sp * (N_NODES * D_OUT / 4)];
            s.x += v.x; s.y += v.y; s.z += v.z; s.w += v.w;
        }
        const float sc = dis[gid >> 4];
        float4 o;
        o.x = fmaxf(s.x * sc, 0.f);
        o.y = fmaxf(s.y * sc, 0.f);
        o.z = fmaxf(s.z * sc, 0.f);
        o.w = fmaxf(s.w * sc, 0.f);
        ((float4*)out)[gid] = o;
    }
}

// ---- Fused cooperative kernel ----
__global__ __launch_bounds__(256, 2) void k_fused(
    const float* __restrict__ A, const float* __restrict__ X,
    const float* __restrict__ W, float* __restrict__ dis,
    unsigned short* __restrict__ A16, unsigned short* __restrict__ Gp,
    float* __restrict__ partial, float* __restrict__ out)
{
    cg::grid_group grid = cg::this_grid();
    const int bid = blockIdx.x, nb = gridDim.x, tid = threadIdx.x;
    phase1(A, dis, A16, bid, nb, tid);
    grid.sync();
    phase2(X, W, dis, Gp, bid, nb, tid);
    grid.sync();
    phase3(A16, Gp, partial, bid, nb, tid);
    grid.sync();
    phase4(partial, dis, out, bid, nb, tid);
}

// ---- Fallback standalone kernels (same phases, separate dispatches) ----
__global__ __launch_bounds__(256) void k_p1(const float* __restrict__ A,
                                            float* __restrict__ dis,
                                            unsigned short* __restrict__ A16) {
    phase1(A, dis, A16, blockIdx.x, gridDim.x, threadIdx.x);
}
__global__ __launch_bounds__(256) void k_p2(const float* __restrict__ X,
                                            const float* __restrict__ W,
                                            const float* __restrict__ dis,
                                            unsigned short* __restrict__ Gp) {
    phase2(X, W, dis, Gp, blockIdx.x, gridDim.x, threadIdx.x);
}
__global__ __launch_bounds__(256) void k_p3(const unsigned short* __restrict__ A16,
                                            const unsigned short* __restrict__ Gp,
                                            float* __restrict__ partial) {
    phase3(A16, Gp, partial, blockIdx.x, gridDim.x, threadIdx.x);
}
__global__ __launch_bounds__(256) void k_p4(const float* __restrict__ partial,
                                            const float* __restrict__ dis,
                                            float* __restrict__ out) {
    phase4(partial, dis, out, blockIdx.x, gridDim.x, threadIdx.x);
}

extern "C" void kernel_launch(void* const* d_in, const int* in_sizes, int n_in,
                              void* d_out, int out_size, void* d_ws, size_t ws_size,
                              hipStream_t stream) {
    const float* X = (const float*)d_in[0];
    const float* A = (const float*)d_in[1];
    const float* W = (const float*)d_in[2];
    float* out = (float*)d_out;

    char* ws = (char*)d_ws;
    float*          dis     = (float*)ws;                                      // 32 KB
    unsigned short* Gp      = (unsigned short*)(ws + (1u << 20));              // 1 MB
    unsigned short* A16     = (unsigned short*)(ws + (2u << 20));              // 128 MB
    float*          partial = (float*)(ws + (2u << 20) + ((size_t)128 << 20)); // 16 MB

    // Host-side occupancy query (capture-safe): size the cooperative grid.
    int perCU = 0;
    if (hipOccupancyMaxActiveBlocksPerMultiprocessor(&perCU, (const void*)k_fused,
                                                     256, 0) != hipSuccess || perCU < 1)
        perCU = 1;
    int nblk = perCU * 256;
    if (nblk > MAXGRID) nblk = MAXGRID;

    void* args[] = { (void*)&A, (void*)&X, (void*)&W, (void*)&dis,
                     (void*)&A16, (void*)&Gp, (void*)&partial, (void*)&out };
    hipError_t err = hipLaunchCooperativeKernel((const void*)k_fused, dim3(nblk),
                                                dim3(256), args, 0, stream);
    if (err != hipSuccess) {
        // Fallback: identical phases as 4 ordinary dispatches (stream-ordered).
        k_p1<<<2048, 256, 0, stream>>>(A, dis, A16);
        k_p2<<<256, 256, 0, stream>>>(X, W, dis, Gp);
        k_p3<<<512, 256, 0, stream>>>(A16, Gp, partial);
        k_p4<<<512, 256, 0, stream>>>(partial, dis, out);
    }
}

// Round 5
// 461.704 us; speedup vs baseline: 1.3458x; 1.3458x over previous
//
#include <hip/hip_runtime.h>

#define N_NODES 8192
#define D_IN    128
#define D_OUT   64
#define NSPLIT  32

typedef __attribute__((ext_vector_type(8))) short short8;
typedef __attribute__((ext_vector_type(4))) float f32x4;

__device__ __forceinline__ short f2bf(float f) {
    unsigned u = __builtin_bit_cast(unsigned, f);
    u += 0x7fff + ((u >> 16) & 1);
    return (short)(u >> 16);
}

// ---- K1: dis[i] = rsqrt(rowsum(A[i,:])). Pure read, one wave/row. ----
// 2048 blocks x 256 (32 waves/CU). 8 loads batched -> 8KB in flight per wave.
__global__ __launch_bounds__(256) void k_deg(const float* __restrict__ A,
                                             float* __restrict__ dis) {
    const int wave = threadIdx.x >> 6, lane = threadIdx.x & 63;
    const int row = blockIdx.x * 4 + wave;
    const float4* Ar = (const float4*)(A + (size_t)row * N_NODES);
    float s = 0.f;
#pragma unroll
    for (int i = 0; i < 4; ++i) {
        float4 v[8];
#pragma unroll
        for (int j = 0; j < 8; ++j) v[j] = Ar[lane + 64 * (i * 8 + j)];
#pragma unroll
        for (int j = 0; j < 8; ++j) s += (v[j].x + v[j].y) + (v[j].z + v[j].w);
    }
#pragma unroll
    for (int off = 32; off; off >>= 1) s += __shfl_down(s, off, 64);
    if (lane == 0) dis[row] = rsqrtf(s);
}

// ---- K2: G = (diag(dis)*X)@W packed in MFMA B-frag order (R1/R2/R4-verified)
// k=(t,quad,j): t=k>>5, quad=(k>>3)&3, j=k&7;  elem at ((t*4+(n>>4))*64+quad*16+(n&15))*8+j
__global__ __launch_bounds__(256) void k_gpack(const float* __restrict__ X,
                                               const float* __restrict__ W,
                                               const float* __restrict__ dis,
                                               unsigned short* __restrict__ Gp) {
    const int gid = blockIdx.x * 256 + threadIdx.x;   // 65536 = 8192 k x 8 n-groups
    if (gid >= N_NODES * 8) return;
    const int k = gid >> 3;
    const int n0 = (gid & 7) * 8;
    float acc[8] = {0.f,0.f,0.f,0.f,0.f,0.f,0.f,0.f};
    const float4* Xr = (const float4*)(X + (size_t)k * D_IN);
#pragma unroll 4
    for (int d4 = 0; d4 < 32; ++d4) {
        float4 xv = Xr[d4];
        const float* w = W + (d4 * 4) * D_OUT + n0;
#pragma unroll
        for (int q = 0; q < 4; ++q) {
            float x = (q == 0) ? xv.x : (q == 1) ? xv.y : (q == 2) ? xv.z : xv.w;
            float4 w0 = ((const float4*)(w + q * D_OUT))[0];
            float4 w1 = ((const float4*)(w + q * D_OUT))[1];
            acc[0] += x * w0.x; acc[1] += x * w0.y;
            acc[2] += x * w0.z; acc[3] += x * w0.w;
            acc[4] += x * w1.x; acc[5] += x * w1.y;
            acc[6] += x * w1.z; acc[7] += x * w1.w;
        }
    }
    const float scale = dis[k];
    const int t = k >> 5, quad = (k >> 3) & 3, j = k & 7;
#pragma unroll
    for (int c = 0; c < 8; ++c) {
        int n = n0 + c;
        Gp[(((size_t)t * 4 + (n >> 4)) * 64 + quad * 16 + (n & 15)) * 8 + j] =
            (unsigned short)f2bf(acc[c] * scale);
    }
}

// ---- K3: partial[split] = A_rowchunk @ G. fp32 A loads, in-register bf16 pack,
// MFMA 16x16x32. Block = 4 waves x 2 row-tiles = 128 rows. Grid (64, NSPLIT). ----
__global__ __launch_bounds__(256, 4) void k_spmm(const float* __restrict__ A,
                                                 const unsigned short* __restrict__ Gp,
                                                 float* __restrict__ partial) {
    const int lane = threadIdx.x & 63, wave = threadIdx.x >> 6;
    const int quad = lane >> 4, l15 = lane & 15;
    const int rowbase = blockIdx.x * 128 + wave * 32;
    const float* Ar0 = A + (size_t)(rowbase + l15) * N_NODES;
    const float* Ar1 = A + (size_t)(rowbase + 16 + l15) * N_NODES;
    const short8* Gq = (const short8*)Gp;
    const int kt0 = blockIdx.y * (N_NODES / 32 / NSPLIT);   // 8 ktiles per split
    f32x4 acc[2][4] = {};
#pragma unroll 2
    for (int kt = kt0; kt < kt0 + (N_NODES / 32 / NSPLIT); ++kt) {
        const int col = kt * 32 + quad * 8;
        float4 a0lo = *(const float4*)(Ar0 + col);
        float4 a0hi = *(const float4*)(Ar0 + col + 4);
        float4 a1lo = *(const float4*)(Ar1 + col);
        float4 a1hi = *(const float4*)(Ar1 + col + 4);
        const short8* gb = Gq + (size_t)kt * 256 + lane;
        short8 b0 = gb[0], b1 = gb[64], b2 = gb[128], b3 = gb[192];
        short8 a0, a1;
        a0[0]=f2bf(a0lo.x); a0[1]=f2bf(a0lo.y); a0[2]=f2bf(a0lo.z); a0[3]=f2bf(a0lo.w);
        a0[4]=f2bf(a0hi.x); a0[5]=f2bf(a0hi.y); a0[6]=f2bf(a0hi.z); a0[7]=f2bf(a0hi.w);
        a1[0]=f2bf(a1lo.x); a1[1]=f2bf(a1lo.y); a1[2]=f2bf(a1lo.z); a1[3]=f2bf(a1lo.w);
        a1[4]=f2bf(a1hi.x); a1[5]=f2bf(a1hi.y); a1[6]=f2bf(a1hi.z); a1[7]=f2bf(a1hi.w);
        acc[0][0] = __builtin_amdgcn_mfma_f32_16x16x32_bf16(a0, b0, acc[0][0], 0, 0, 0);
        acc[1][0] = __builtin_amdgcn_mfma_f32_16x16x32_bf16(a1, b0, acc[1][0], 0, 0, 0);
        acc[0][1] = __builtin_amdgcn_mfma_f32_16x16x32_bf16(a0, b1, acc[0][1], 0, 0, 0);
        acc[1][1] = __builtin_amdgcn_mfma_f32_16x16x32_bf16(a1, b1, acc[1][1], 0, 0, 0);
        acc[0][2] = __builtin_amdgcn_mfma_f32_16x16x32_bf16(a0, b2, acc[0][2], 0, 0, 0);
        acc[1][2] = __builtin_amdgcn_mfma_f32_16x16x32_bf16(a1, b2, acc[1][2], 0, 0, 0);
        acc[0][3] = __builtin_amdgcn_mfma_f32_16x16x32_bf16(a0, b3, acc[0][3], 0, 0, 0);
        acc[1][3] = __builtin_amdgcn_mfma_f32_16x16x32_bf16(a1, b3, acc[1][3], 0, 0, 0);
    }
    // C/D: row = quad*4 + r, col = u*16 + l15 (verified)
    float* P = partial + (size_t)blockIdx.y * (N_NODES * D_OUT);
#pragma unroll
    for (int rt = 0; rt < 2; ++rt)
#pragma unroll
        for (int u = 0; u < 4; ++u)
#pragma unroll
            for (int r = 0; r < 4; ++r)
                P[(size_t)(rowbase + rt * 16 + quad * 4 + r) * D_OUT + u * 16 + l15] =
                    acc[rt][u][r];
}

// ---- K4: out = relu(dis[row] * sum_s partial[s]) ----
__global__ __launch_bounds__(256) void k_out(const float* __restrict__ partial,
                                             const float* __restrict__ dis,
                                             float* __restrict__ out) {
    const int gid = blockIdx.x * 256 + threadIdx.x;   // float4 idx, 131072
    const float4* p4 = (const float4*)partial;
    float4 s = p4[gid];
#pragma unroll
    for (int sp = 1; sp < NSPLIT; ++sp) {
        float4 v = p4[gid + (size_t)sp * (N_NODES * D_OUT / 4)];
        s.x += v.x; s.y += v.y; s.z += v.z; s.w += v.w;
    }
    const float sc = dis[gid >> 4];
    float4 o;
    o.x = fmaxf(s.x * sc, 0.f);
    o.y = fmaxf(s.y * sc, 0.f);
    o.z = fmaxf(s.z * sc, 0.f);
    o.w = fmaxf(s.w * sc, 0.f);
    ((float4*)out)[gid] = o;
}

extern "C" void kernel_launch(void* const* d_in, const int* in_sizes, int n_in,
                              void* d_out, int out_size, void* d_ws, size_t ws_size,
                              hipStream_t stream) {
    const float* X = (const float*)d_in[0];
    const float* A = (const float*)d_in[1];
    const float* W = (const float*)d_in[2];
    float* out = (float*)d_out;

    char* ws = (char*)d_ws;
    float*          dis     = (float*)ws;                      // 32 KB
    unsigned short* Gp      = (unsigned short*)(ws + (1u << 20));   // 1 MB
    float*          partial = (float*)(ws + (4u << 20));       // 64 MB (NSPLIT=32)

    k_deg  <<<N_NODES / 4, 256, 0, stream>>>(A, dis);
    k_gpack<<<N_NODES * 8 / 256, 256, 0, stream>>>(X, W, dis, Gp);
    k_spmm <<<dim3(N_NODES / 128, NSPLIT), 256, 0, stream>>>(A, Gp, partial);
    k_out  <<<(N_NODES * D_OUT / 4) / 256, 256, 0, stream>>>(partial, dis, out);
}